// Round 1
// baseline (495.170 us; speedup 1.0000x reference)
//
#include <hip/hip_runtime.h>
#include <hip/hip_bf16.h>
#include <stdint.h>

// Problem constants
#define BB 8
#define CC 512
#define NN 9216                    // 96*96
#define CN ((size_t)CC * NN)

typedef __attribute__((ext_vector_type(8))) short bf16x8;
typedef __attribute__((ext_vector_type(4))) float f32x4;

// async global->LDS, 16B per lane; LDS dest = wave-uniform base + lane*16
#define GLDS16(g, l)                                                        \
  __builtin_amdgcn_global_load_lds(                                        \
      (const __attribute__((address_space(1))) void*)(g),                  \
      (__attribute__((address_space(3))) void*)(l), 16, 0, 0)

__device__ inline uint16_t f2bf(float f) {
  union { float f; uint32_t u; } a; a.f = f;
  uint32_t u = a.u;
  return (uint16_t)((u + 0x7FFFu + ((u >> 16) & 1u)) >> 16);  // RNE
}

// ---------------------------------------------------------------------------
// Kernel 1: per-(b,n) channel reduce (max + mean) -> x3, and bf16 cast -> qbf
// grid: 8*9 = 72 blocks x 256 thr; each thread owns 4 consecutive n (float4)
// ---------------------------------------------------------------------------
__global__ __launch_bounds__(256) void k_prep(const float* __restrict__ x,
                                              uint16_t* __restrict__ qbf,
                                              float* __restrict__ x3) {
  int bid = blockIdx.x;
  int b = bid / 9;
  int n0 = (bid % 9) * 1024 + threadIdx.x * 4;
  const float* xb = x + (size_t)b * CN;
  uint16_t* qb = qbf + (size_t)b * CN;
  float mx0 = -1e30f, mx1 = -1e30f, mx2 = -1e30f, mx3 = -1e30f;
  float s0 = 0.f, s1 = 0.f, s2 = 0.f, s3 = 0.f;
  for (int c = 0; c < CC; ++c) {
    float4 v = *(const float4*)&xb[(size_t)c * NN + n0];
    mx0 = fmaxf(mx0, v.x); s0 += v.x;
    mx1 = fmaxf(mx1, v.y); s1 += v.y;
    mx2 = fmaxf(mx2, v.z); s2 += v.z;
    mx3 = fmaxf(mx3, v.w); s3 += v.w;
    ushort4 u;
    u.x = f2bf(v.x); u.y = f2bf(v.y); u.z = f2bf(v.z); u.w = f2bf(v.w);
    *(ushort4*)&qb[(size_t)c * NN + n0] = u;
  }
  float4 o;
  o.x = mx0 + s0 * (1.f / CC);
  o.y = mx1 + s1 * (1.f / CC);
  o.z = mx2 + s2 * (1.f / CC);
  o.w = mx3 + s3 * (1.f / CC);
  *(float4*)&x3[(size_t)b * NN + n0] = o;
}

// ---------------------------------------------------------------------------
// Kernel 2: transpose qbf [b][c][n] -> qt [b][n][c]  (64x64 LDS tiles)
// grid: 8 * 8 * 144 = 9216 blocks x 256 thr
// ---------------------------------------------------------------------------
__global__ __launch_bounds__(256) void k_qt(const uint16_t* __restrict__ qbf,
                                            uint16_t* __restrict__ qt) {
  __shared__ uint16_t tile[64][68];  // pad to 68 to break bank conflicts
  int bid = blockIdx.x;
  int b = bid / 1152;
  int rem = bid % 1152;
  int d0 = (rem / 144) * 64;
  int n0 = (rem % 144) * 64;
  int t = threadIdx.x;
  int cg = (t & 15) * 4;  // 4-element column group
  int rr = t >> 4;        // 0..15
  const uint16_t* src = qbf + (size_t)b * CN + (size_t)d0 * NN + n0;
  for (int rb = 0; rb < 4; ++rb) {
    int d = rr + rb * 16;
    ushort4 v = *(const ushort4*)&src[(size_t)d * NN + cg];
    tile[d][cg + 0] = v.x; tile[d][cg + 1] = v.y;
    tile[d][cg + 2] = v.z; tile[d][cg + 3] = v.w;
  }
  __syncthreads();
  uint16_t* dst = qt + (size_t)b * CN + (size_t)n0 * CC + d0;
  for (int rb = 0; rb < 4; ++rb) {
    int n = rr + rb * 16;
    ushort4 v;
    v.x = tile[cg + 0][n]; v.y = tile[cg + 1][n];
    v.z = tile[cg + 2][n]; v.w = tile[cg + 3][n];
    *(ushort4*)&dst[(size_t)n * CC + cg] = v;
  }
}

// ---------------------------------------------------------------------------
// Kernel 3: GEMM1  energy[b] = Q @ Q^T   (M=N=512, K=9216, NT layout)
// 128x128 tile, BK=32, 256 thr (4 waves, 2x2 of 64x64), mfma 16x16x32 bf16
// grid: 8 * 16 = 128 blocks
// ---------------------------------------------------------------------------
__global__ __launch_bounds__(256) void k_gemm1(const uint16_t* __restrict__ q,
                                               float* __restrict__ energy) {
  __shared__ uint16_t As[128 * 32];
  __shared__ uint16_t Bs[128 * 32];
  int bid = blockIdx.x;
  int b = bid >> 4;
  int tmi = (bid >> 2) & 3, tni = bid & 3;
  const uint16_t* Abase = q + (size_t)b * CN + (size_t)(tmi * 128) * NN;
  const uint16_t* Bbase = q + (size_t)b * CN + (size_t)(tni * 128) * NN;
  int tid = threadIdx.x, lane = tid & 63, wid = tid >> 6;
  int wm = (wid >> 1) * 64, wn = (wid & 1) * 64;
  int lr = lane & 15, lq = lane >> 4;
  // staging: thread's two 16B chunks (8 bf16 each) of the 128x32 tile
  int e0 = tid * 8;
  int r0 = e0 >> 5, c0 = e0 & 31;
  int r1 = (e0 + 2048) >> 5, c1 = (e0 + 2048) & 31;
  int ldsb0 = wid * 512;          // wave-uniform LDS base (elements)
  int ldsb1 = 2048 + ldsb0;
  f32x4 acc[4][4];
  for (int i = 0; i < 4; ++i)
    for (int j = 0; j < 4; ++j)
      for (int k = 0; k < 4; ++k) acc[i][j][k] = 0.f;

  for (int k0 = 0; k0 < NN; k0 += 32) {
    GLDS16(Abase + (size_t)r0 * NN + k0 + c0, &As[ldsb0]);
    GLDS16(Abase + (size_t)r1 * NN + k0 + c1, &As[ldsb1]);
    GLDS16(Bbase + (size_t)r0 * NN + k0 + c0, &Bs[ldsb0]);
    GLDS16(Bbase + (size_t)r1 * NN + k0 + c1, &Bs[ldsb1]);
    __syncthreads();
    bf16x8 av[4], bv[4];
    for (int mr = 0; mr < 4; ++mr)
      av[mr] = *(const bf16x8*)&As[(wm + mr * 16 + lr) * 32 + lq * 8];
    for (int nr = 0; nr < 4; ++nr)
      bv[nr] = *(const bf16x8*)&Bs[(wn + nr * 16 + lr) * 32 + lq * 8];
    for (int mr = 0; mr < 4; ++mr)
      for (int nr = 0; nr < 4; ++nr)
        acc[mr][nr] = __builtin_amdgcn_mfma_f32_16x16x32_bf16(
            av[mr], bv[nr], acc[mr][nr], 0, 0, 0);
    __syncthreads();
  }
  float* eb = energy + (size_t)b * CC * CC;
  for (int mr = 0; mr < 4; ++mr)
    for (int nr = 0; nr < 4; ++nr) {
      int col = tni * 128 + wn + nr * 16 + lr;
      for (int j = 0; j < 4; ++j) {
        int row = tmi * 128 + wm + mr * 16 + lq * 4 + j;
        eb[(size_t)row * CC + col] = acc[mr][nr][j];
      }
    }
}

// ---------------------------------------------------------------------------
// Kernel 4: row softmax of (rowmax - energy) == exp(rowmin - e)/sum
// one wave per row; grid: 8*512 = 4096 blocks x 64 thr
// ---------------------------------------------------------------------------
__global__ __launch_bounds__(64) void k_softmax(const float* __restrict__ energy,
                                                uint16_t* __restrict__ att) {
  int row = blockIdx.x;
  const float* e = energy + (size_t)row * CC;
  int lane = threadIdx.x;
  float4 v0 = *(const float4*)&e[lane * 8];
  float4 v1 = *(const float4*)&e[lane * 8 + 4];
  float mn = fminf(fminf(fminf(v0.x, v0.y), fminf(v0.z, v0.w)),
                   fminf(fminf(v1.x, v1.y), fminf(v1.z, v1.w)));
  for (int off = 32; off; off >>= 1) mn = fminf(mn, __shfl_xor(mn, off));
  float p0 = __expf(mn - v0.x), p1 = __expf(mn - v0.y);
  float p2 = __expf(mn - v0.z), p3 = __expf(mn - v0.w);
  float p4 = __expf(mn - v1.x), p5 = __expf(mn - v1.y);
  float p6 = __expf(mn - v1.z), p7 = __expf(mn - v1.w);
  float s = ((p0 + p1) + (p2 + p3)) + ((p4 + p5) + (p6 + p7));
  for (int off = 32; off; off >>= 1) s += __shfl_xor(s, off);
  float inv = 1.f / s;
  ushort4 u0, u1;
  u0.x = f2bf(p0 * inv); u0.y = f2bf(p1 * inv);
  u0.z = f2bf(p2 * inv); u0.w = f2bf(p3 * inv);
  u1.x = f2bf(p4 * inv); u1.y = f2bf(p5 * inv);
  u1.z = f2bf(p6 * inv); u1.w = f2bf(p7 * inv);
  uint16_t* a = att + (size_t)row * CC + lane * 8;
  *(ushort4*)&a[0] = u0;
  *(ushort4*)&a[4] = u1;
}

// ---------------------------------------------------------------------------
// Kernel 5: GEMM2  out = gamma * (x3[n] * (att @ q)[c,n]) + x
// A = att [512,512] row-major, Bt = qt [9216,512] row-major (NT), K=512
// 128x128 tile, BK=32; grid: 8 * 4 * 72 = 2304 blocks
// ---------------------------------------------------------------------------
__global__ __launch_bounds__(256) void k_gemm2(const uint16_t* __restrict__ att,
                                               const uint16_t* __restrict__ qt,
                                               const float* __restrict__ x3,
                                               const float* __restrict__ x,
                                               const float* __restrict__ gamma,
                                               float* __restrict__ out) {
  __shared__ uint16_t As[128 * 32];
  __shared__ uint16_t Bs[128 * 32];
  int bid = blockIdx.x;
  int b = bid / 288;
  int rem = bid % 288;
  int tmi = rem / 72;   // c tile (0..3)
  int tni = rem % 72;   // n tile (0..71)
  const uint16_t* Abase = att + (size_t)b * CC * CC + (size_t)(tmi * 128) * CC;
  const uint16_t* Bbase = qt + (size_t)b * CN + (size_t)(tni * 128) * CC;
  int tid = threadIdx.x, lane = tid & 63, wid = tid >> 6;
  int wm = (wid >> 1) * 64, wn = (wid & 1) * 64;
  int lr = lane & 15, lq = lane >> 4;
  int e0 = tid * 8;
  int r0 = e0 >> 5, c0 = e0 & 31;
  int r1 = (e0 + 2048) >> 5, c1 = (e0 + 2048) & 31;
  int ldsb0 = wid * 512;
  int ldsb1 = 2048 + ldsb0;
  f32x4 acc[4][4];
  for (int i = 0; i < 4; ++i)
    for (int j = 0; j < 4; ++j)
      for (int k = 0; k < 4; ++k) acc[i][j][k] = 0.f;

  for (int k0 = 0; k0 < CC; k0 += 32) {
    GLDS16(Abase + (size_t)r0 * CC + k0 + c0, &As[ldsb0]);
    GLDS16(Abase + (size_t)r1 * CC + k0 + c1, &As[ldsb1]);
    GLDS16(Bbase + (size_t)r0 * CC + k0 + c0, &Bs[ldsb0]);
    GLDS16(Bbase + (size_t)r1 * CC + k0 + c1, &Bs[ldsb1]);
    __syncthreads();
    bf16x8 av[4], bv[4];
    for (int mr = 0; mr < 4; ++mr)
      av[mr] = *(const bf16x8*)&As[(wm + mr * 16 + lr) * 32 + lq * 8];
    for (int nr = 0; nr < 4; ++nr)
      bv[nr] = *(const bf16x8*)&Bs[(wn + nr * 16 + lr) * 32 + lq * 8];
    for (int mr = 0; mr < 4; ++mr)
      for (int nr = 0; nr < 4; ++nr)
        acc[mr][nr] = __builtin_amdgcn_mfma_f32_16x16x32_bf16(
            av[mr], bv[nr], acc[mr][nr], 0, 0, 0);
    __syncthreads();
  }
  float g = gamma[0];
  const float* xb = x + (size_t)b * CN;
  const float* x3b = x3 + (size_t)b * NN;
  float* ob = out + (size_t)b * CN;
  for (int mr = 0; mr < 4; ++mr)
    for (int nr = 0; nr < 4; ++nr) {
      int n = tni * 128 + wn + nr * 16 + lr;
      float s = x3b[n];
      for (int j = 0; j < 4; ++j) {
        int c = tmi * 128 + wm + mr * 16 + lq * 4 + j;
        size_t idx = (size_t)c * NN + n;
        ob[idx] = g * (s * acc[mr][nr][j]) + xb[idx];
      }
    }
}

// ---------------------------------------------------------------------------
extern "C" void kernel_launch(void* const* d_in, const int* in_sizes, int n_in,
                              void* d_out, int out_size, void* d_ws, size_t ws_size,
                              hipStream_t stream) {
  const float* x = (const float*)d_in[0];
  const float* gamma = (const float*)d_in[1];
  float* out = (float*)d_out;
  char* ws = (char*)d_ws;
  // workspace layout (163,872,768 B total)
  uint16_t* qbf  = (uint16_t*)(ws);                  // 75,497,472
  uint16_t* qt   = (uint16_t*)(ws + 75497472);       // 75,497,472
  float*    energy = (float*)(ws + 150994944);       //  8,388,608
  uint16_t* att  = (uint16_t*)(ws + 159383552);      //  4,194,304
  float*    x3   = (float*)(ws + 163577856);         //    294,912

  k_prep<<<72, 256, 0, stream>>>(x, qbf, x3);
  k_qt<<<9216, 256, 0, stream>>>(qbf, qt);
  k_gemm1<<<128, 256, 0, stream>>>(qbf, energy);
  k_softmax<<<4096, 64, 0, stream>>>(energy, att);
  k_gemm2<<<2304, 256, 0, stream>>>(att, qt, x3, x, gamma, out);
}

// Round 2
// 325.695 us; speedup vs baseline: 1.5203x; 1.5203x over previous
//
#include <hip/hip_runtime.h>
#include <hip/hip_bf16.h>
#include <stdint.h>

// Problem constants
#define BB 8
#define CC 512
#define NN 9216                    // 96*96
#define CN ((size_t)CC * NN)

typedef __attribute__((ext_vector_type(8))) short bf16x8;
typedef __attribute__((ext_vector_type(4))) float f32x4;

// async global->LDS, 16B per lane; LDS dest = wave-uniform base + lane*16
#define GLDS16(g, l)                                                        \
  __builtin_amdgcn_global_load_lds(                                        \
      (const __attribute__((address_space(1))) void*)(g),                  \
      (__attribute__((address_space(3))) void*)(l), 16, 0, 0)

__device__ inline uint16_t f2bf(float f) {
  union { float f; uint32_t u; } a; a.f = f;
  uint32_t u = a.u;
  return (uint16_t)((u + 0x7FFFu + ((u >> 16) & 1u)) >> 16);  // RNE
}

// ---------------------------------------------------------------------------
// Kernel 1a: partial channel reduce over 64-channel chunks + bf16 cast
// grid: 8 b * 9 n-chunks * 8 c-chunks = 576 blocks x 256 thr
// each thread owns 4 consecutive n (float4), loops 64 channels
// ---------------------------------------------------------------------------
__global__ __launch_bounds__(256) void k_prep1(const float* __restrict__ x,
                                               uint16_t* __restrict__ qbf,
                                               float* __restrict__ pmax,
                                               float* __restrict__ psum) {
  int bid = blockIdx.x;
  int b = bid / 72;
  int rem = bid % 72;
  int nch = rem / 8;
  int cch = rem % 8;
  int n0 = nch * 1024 + threadIdx.x * 4;
  int c0 = cch * 64;
  const float* xb = x + (size_t)b * CN;
  uint16_t* qb = qbf + (size_t)b * CN;
  float mx0 = -1e30f, mx1 = -1e30f, mx2 = -1e30f, mx3 = -1e30f;
  float s0 = 0.f, s1 = 0.f, s2 = 0.f, s3 = 0.f;
  for (int c = c0; c < c0 + 64; ++c) {
    float4 v = *(const float4*)&xb[(size_t)c * NN + n0];
    mx0 = fmaxf(mx0, v.x); s0 += v.x;
    mx1 = fmaxf(mx1, v.y); s1 += v.y;
    mx2 = fmaxf(mx2, v.z); s2 += v.z;
    mx3 = fmaxf(mx3, v.w); s3 += v.w;
    ushort4 u;
    u.x = f2bf(v.x); u.y = f2bf(v.y); u.z = f2bf(v.z); u.w = f2bf(v.w);
    *(ushort4*)&qb[(size_t)c * NN + n0] = u;
  }
  size_t pidx = ((size_t)(b * 8 + cch)) * NN + n0;
  float4 m4; m4.x = mx0; m4.y = mx1; m4.z = mx2; m4.w = mx3;
  float4 s4; s4.x = s0;  s4.y = s1;  s4.z = s2;  s4.w = s3;
  *(float4*)&pmax[pidx] = m4;
  *(float4*)&psum[pidx] = s4;
}

// ---------------------------------------------------------------------------
// Kernel 1b: combine 8 channel-chunk partials -> x3 = max + mean
// grid: 72 blocks x 256 thr, 4 n per thread
// ---------------------------------------------------------------------------
__global__ __launch_bounds__(256) void k_prep2(const float* __restrict__ pmax,
                                               const float* __restrict__ psum,
                                               float* __restrict__ x3) {
  int bid = blockIdx.x;
  int b = bid / 9;
  int n0 = (bid % 9) * 1024 + threadIdx.x * 4;
  float4 mx = *(const float4*)&pmax[(size_t)(b * 8) * NN + n0];
  float4 sm = *(const float4*)&psum[(size_t)(b * 8) * NN + n0];
  for (int cch = 1; cch < 8; ++cch) {
    float4 m = *(const float4*)&pmax[(size_t)(b * 8 + cch) * NN + n0];
    float4 s = *(const float4*)&psum[(size_t)(b * 8 + cch) * NN + n0];
    mx.x = fmaxf(mx.x, m.x); mx.y = fmaxf(mx.y, m.y);
    mx.z = fmaxf(mx.z, m.z); mx.w = fmaxf(mx.w, m.w);
    sm.x += s.x; sm.y += s.y; sm.z += s.z; sm.w += s.w;
  }
  float4 o;
  o.x = mx.x + sm.x * (1.f / CC);
  o.y = mx.y + sm.y * (1.f / CC);
  o.z = mx.z + sm.z * (1.f / CC);
  o.w = mx.w + sm.w * (1.f / CC);
  *(float4*)&x3[(size_t)b * NN + n0] = o;
}

// ---------------------------------------------------------------------------
// Kernel 2: transpose qbf [b][c][n] -> qt [b][n][c]  (64x64 LDS tiles)
// grid: 8 * 8 * 144 = 9216 blocks x 256 thr
// ---------------------------------------------------------------------------
__global__ __launch_bounds__(256) void k_qt(const uint16_t* __restrict__ qbf,
                                            uint16_t* __restrict__ qt) {
  __shared__ uint16_t tile[64][68];  // pad to 68 to break bank conflicts
  int bid = blockIdx.x;
  int b = bid / 1152;
  int rem = bid % 1152;
  int d0 = (rem / 144) * 64;
  int n0 = (rem % 144) * 64;
  int t = threadIdx.x;
  int cg = (t & 15) * 4;  // 4-element column group
  int rr = t >> 4;        // 0..15
  const uint16_t* src = qbf + (size_t)b * CN + (size_t)d0 * NN + n0;
  for (int rb = 0; rb < 4; ++rb) {
    int d = rr + rb * 16;
    ushort4 v = *(const ushort4*)&src[(size_t)d * NN + cg];
    tile[d][cg + 0] = v.x; tile[d][cg + 1] = v.y;
    tile[d][cg + 2] = v.z; tile[d][cg + 3] = v.w;
  }
  __syncthreads();
  uint16_t* dst = qt + (size_t)b * CN + (size_t)n0 * CC + d0;
  for (int rb = 0; rb < 4; ++rb) {
    int n = rr + rb * 16;
    ushort4 v;
    v.x = tile[cg + 0][n]; v.y = tile[cg + 1][n];
    v.z = tile[cg + 2][n]; v.w = tile[cg + 3][n];
    *(ushort4*)&dst[(size_t)n * CC + cg] = v;
  }
}

// ---------------------------------------------------------------------------
// Kernel 3: GEMM1  energy[b] = Q @ Q^T   (M=N=512, K=9216, NT layout)
// 128x64 tile, BK=32, 256 thr (4 waves 2x2, each wave 64x32), mfma 16x16x32
// grid: 8 * 4 * 8 = 256 blocks  (full CU coverage)
// ---------------------------------------------------------------------------
__global__ __launch_bounds__(256) void k_gemm1(const uint16_t* __restrict__ q,
                                               float* __restrict__ energy) {
  __shared__ uint16_t As[128 * 32];
  __shared__ uint16_t Bs[64 * 32];
  int bid = blockIdx.x;
  int b = bid >> 5;
  int rem = bid & 31;
  int tmi = rem >> 3;   // 0..3  (128-row tile)
  int tni = rem & 7;    // 0..7  (64-col tile)
  const uint16_t* Abase = q + (size_t)b * CN + (size_t)(tmi * 128) * NN;
  const uint16_t* Bbase = q + (size_t)b * CN + (size_t)(tni * 64) * NN;
  int tid = threadIdx.x, lane = tid & 63, wid = tid >> 6;
  int wm = (wid >> 1) * 64, wn = (wid & 1) * 32;
  int lr = lane & 15, lq = lane >> 4;
  int e0 = tid * 8;
  int r0 = e0 >> 5, c0 = e0 & 31;   // A rows 0..63 / B rows 0..63
  int ldsb = wid * 512;             // wave-uniform LDS base (elements)
  f32x4 acc[4][2];
  for (int i = 0; i < 4; ++i)
    for (int j = 0; j < 2; ++j)
      for (int k = 0; k < 4; ++k) acc[i][j][k] = 0.f;

  for (int k0 = 0; k0 < NN; k0 += 32) {
    GLDS16(Abase + (size_t)r0 * NN + k0 + c0, &As[ldsb]);
    GLDS16(Abase + (size_t)(r0 + 64) * NN + k0 + c0, &As[2048 + ldsb]);
    GLDS16(Bbase + (size_t)r0 * NN + k0 + c0, &Bs[ldsb]);
    __syncthreads();
    bf16x8 av[4], bv[2];
    for (int mr = 0; mr < 4; ++mr)
      av[mr] = *(const bf16x8*)&As[(wm + mr * 16 + lr) * 32 + lq * 8];
    for (int nr = 0; nr < 2; ++nr)
      bv[nr] = *(const bf16x8*)&Bs[(wn + nr * 16 + lr) * 32 + lq * 8];
    for (int mr = 0; mr < 4; ++mr)
      for (int nr = 0; nr < 2; ++nr)
        acc[mr][nr] = __builtin_amdgcn_mfma_f32_16x16x32_bf16(
            av[mr], bv[nr], acc[mr][nr], 0, 0, 0);
    __syncthreads();
  }
  float* eb = energy + (size_t)b * CC * CC;
  for (int mr = 0; mr < 4; ++mr)
    for (int nr = 0; nr < 2; ++nr) {
      int col = tni * 64 + wn + nr * 16 + lr;
      for (int j = 0; j < 4; ++j) {
        int row = tmi * 128 + wm + mr * 16 + lq * 4 + j;
        eb[(size_t)row * CC + col] = acc[mr][nr][j];
      }
    }
}

// ---------------------------------------------------------------------------
// Kernel 4: row softmax of (rowmax - energy) == exp(rowmin - e)/sum
// one wave per row; grid: 8*512 = 4096 blocks x 64 thr
// ---------------------------------------------------------------------------
__global__ __launch_bounds__(64) void k_softmax(const float* __restrict__ energy,
                                                uint16_t* __restrict__ att) {
  int row = blockIdx.x;
  const float* e = energy + (size_t)row * CC;
  int lane = threadIdx.x;
  float4 v0 = *(const float4*)&e[lane * 8];
  float4 v1 = *(const float4*)&e[lane * 8 + 4];
  float mn = fminf(fminf(fminf(v0.x, v0.y), fminf(v0.z, v0.w)),
                   fminf(fminf(v1.x, v1.y), fminf(v1.z, v1.w)));
  for (int off = 32; off; off >>= 1) mn = fminf(mn, __shfl_xor(mn, off));
  float p0 = __expf(mn - v0.x), p1 = __expf(mn - v0.y);
  float p2 = __expf(mn - v0.z), p3 = __expf(mn - v0.w);
  float p4 = __expf(mn - v1.x), p5 = __expf(mn - v1.y);
  float p6 = __expf(mn - v1.z), p7 = __expf(mn - v1.w);
  float s = ((p0 + p1) + (p2 + p3)) + ((p4 + p5) + (p6 + p7));
  for (int off = 32; off; off >>= 1) s += __shfl_xor(s, off);
  float inv = 1.f / s;
  ushort4 u0, u1;
  u0.x = f2bf(p0 * inv); u0.y = f2bf(p1 * inv);
  u0.z = f2bf(p2 * inv); u0.w = f2bf(p3 * inv);
  u1.x = f2bf(p4 * inv); u1.y = f2bf(p5 * inv);
  u1.z = f2bf(p6 * inv); u1.w = f2bf(p7 * inv);
  uint16_t* a = att + (size_t)row * CC + lane * 8;
  *(ushort4*)&a[0] = u0;
  *(ushort4*)&a[4] = u1;
}

// ---------------------------------------------------------------------------
// Kernel 5: GEMM2  out = gamma * (x3[n] * (att @ q)[c,n]) + x
// A = att [512,512] row-major, Bt = qt [9216,512] row-major (NT), K=512
// 128x128 tile, BK=32; grid: 8 * 4 * 72 = 2304 blocks
// ---------------------------------------------------------------------------
__global__ __launch_bounds__(256) void k_gemm2(const uint16_t* __restrict__ att,
                                               const uint16_t* __restrict__ qt,
                                               const float* __restrict__ x3,
                                               const float* __restrict__ x,
                                               const float* __restrict__ gamma,
                                               float* __restrict__ out) {
  __shared__ uint16_t As[128 * 32];
  __shared__ uint16_t Bs[128 * 32];
  int bid = blockIdx.x;
  int b = bid / 288;
  int rem = bid % 288;
  int tmi = rem / 72;   // c tile (0..3)
  int tni = rem % 72;   // n tile (0..71)
  const uint16_t* Abase = att + (size_t)b * CC * CC + (size_t)(tmi * 128) * CC;
  const uint16_t* Bbase = qt + (size_t)b * CN + (size_t)(tni * 128) * CC;
  int tid = threadIdx.x, lane = tid & 63, wid = tid >> 6;
  int wm = (wid >> 1) * 64, wn = (wid & 1) * 64;
  int lr = lane & 15, lq = lane >> 4;
  int e0 = tid * 8;
  int r0 = e0 >> 5, c0 = e0 & 31;
  int r1 = (e0 + 2048) >> 5, c1 = (e0 + 2048) & 31;
  int ldsb0 = wid * 512;
  int ldsb1 = 2048 + ldsb0;
  f32x4 acc[4][4];
  for (int i = 0; i < 4; ++i)
    for (int j = 0; j < 4; ++j)
      for (int k = 0; k < 4; ++k) acc[i][j][k] = 0.f;

  for (int k0 = 0; k0 < CC; k0 += 32) {
    GLDS16(Abase + (size_t)r0 * CC + k0 + c0, &As[ldsb0]);
    GLDS16(Abase + (size_t)r1 * CC + k0 + c1, &As[ldsb1]);
    GLDS16(Bbase + (size_t)r0 * CC + k0 + c0, &Bs[ldsb0]);
    GLDS16(Bbase + (size_t)r1 * CC + k0 + c1, &Bs[ldsb1]);
    __syncthreads();
    bf16x8 av[4], bv[4];
    for (int mr = 0; mr < 4; ++mr)
      av[mr] = *(const bf16x8*)&As[(wm + mr * 16 + lr) * 32 + lq * 8];
    for (int nr = 0; nr < 4; ++nr)
      bv[nr] = *(const bf16x8*)&Bs[(wn + nr * 16 + lr) * 32 + lq * 8];
    for (int mr = 0; mr < 4; ++mr)
      for (int nr = 0; nr < 4; ++nr)
        acc[mr][nr] = __builtin_amdgcn_mfma_f32_16x16x32_bf16(
            av[mr], bv[nr], acc[mr][nr], 0, 0, 0);
    __syncthreads();
  }
  float g = gamma[0];
  const float* xb = x + (size_t)b * CN;
  const float* x3b = x3 + (size_t)b * NN;
  float* ob = out + (size_t)b * CN;
  for (int mr = 0; mr < 4; ++mr)
    for (int nr = 0; nr < 4; ++nr) {
      int n = tni * 128 + wn + nr * 16 + lr;
      float s = x3b[n];
      for (int j = 0; j < 4; ++j) {
        int c = tmi * 128 + wm + mr * 16 + lq * 4 + j;
        size_t idx = (size_t)c * NN + n;
        ob[idx] = g * (s * acc[mr][nr][j]) + xb[idx];
      }
    }
}

// ---------------------------------------------------------------------------
extern "C" void kernel_launch(void* const* d_in, const int* in_sizes, int n_in,
                              void* d_out, int out_size, void* d_ws, size_t ws_size,
                              hipStream_t stream) {
  const float* x = (const float*)d_in[0];
  const float* gamma = (const float*)d_in[1];
  float* out = (float*)d_out;
  char* ws = (char*)d_ws;
  // workspace layout (163,872,768 B total) — partials alias the energy
  // region: dead before k_gemm1 writes energy (sequential stream order).
  uint16_t* qbf  = (uint16_t*)(ws);                  // 75,497,472
  uint16_t* qt   = (uint16_t*)(ws + 75497472);       // 75,497,472
  float*    energy = (float*)(ws + 150994944);       //  8,388,608
  float*    pmax = (float*)(ws + 150994944);         //  2,359,296 (alias)
  float*    psum = (float*)(ws + 150994944 + 2359296); // 2,359,296 (alias)
  uint16_t* att  = (uint16_t*)(ws + 159383552);      //  4,194,304
  float*    x3   = (float*)(ws + 163577856);         //    294,912

  k_prep1<<<576, 256, 0, stream>>>(x, qbf, pmax, psum);
  k_prep2<<<72, 256, 0, stream>>>(pmax, psum, x3);
  k_qt<<<9216, 256, 0, stream>>>(qbf, qt);
  k_gemm1<<<256, 256, 0, stream>>>(qbf, energy);
  k_softmax<<<4096, 64, 0, stream>>>(energy, att);
  k_gemm2<<<2304, 256, 0, stream>>>(att, qt, x3, x, gamma, out);
}

// Round 3
// 255.220 us; speedup vs baseline: 1.9402x; 1.2761x over previous
//
#include <hip/hip_runtime.h>
#include <hip/hip_bf16.h>
#include <stdint.h>

// Problem constants
#define BB 8
#define CC 512
#define NN 9216                    // 96*96
#define CN ((size_t)CC * NN)
#define SK 8                       // split-K factor for GEMM1
#define KCH (NN / SK)              // 1152 = 36 BK-steps of 32

typedef __attribute__((ext_vector_type(8))) short bf16x8;
typedef __attribute__((ext_vector_type(4))) float f32x4;

// async global->LDS, 16B per lane; LDS dest = wave-uniform base + lane*16
#define GLDS16(g, l)                                                        \
  __builtin_amdgcn_global_load_lds(                                        \
      (const __attribute__((address_space(1))) void*)(g),                  \
      (__attribute__((address_space(3))) void*)(l), 16, 0, 0)

__device__ inline uint16_t f2bf(float f) {
  union { float f; uint32_t u; } a; a.f = f;
  uint32_t u = a.u;
  return (uint16_t)((u + 0x7FFFu + ((u >> 16) & 1u)) >> 16);  // RNE
}

// ---------------------------------------------------------------------------
// Kernel 1a: partial channel reduce over 32-channel chunks + bf16 cast
// grid: 8 b * 9 n-chunks * 16 c-chunks = 1152 blocks x 256 thr
// ---------------------------------------------------------------------------
__global__ __launch_bounds__(256) void k_prep1(const float* __restrict__ x,
                                               uint16_t* __restrict__ qbf,
                                               float* __restrict__ pmax,
                                               float* __restrict__ psum) {
  int bid = blockIdx.x;
  int b = bid / 144;
  int rem = bid % 144;
  int nch = rem / 16;
  int cch = rem % 16;
  int n0 = nch * 1024 + threadIdx.x * 4;
  int c0 = cch * 32;
  const float* xb = x + (size_t)b * CN;
  uint16_t* qb = qbf + (size_t)b * CN;
  float mx0 = -1e30f, mx1 = -1e30f, mx2 = -1e30f, mx3 = -1e30f;
  float s0 = 0.f, s1 = 0.f, s2 = 0.f, s3 = 0.f;
  for (int c = c0; c < c0 + 32; ++c) {
    float4 v = *(const float4*)&xb[(size_t)c * NN + n0];
    mx0 = fmaxf(mx0, v.x); s0 += v.x;
    mx1 = fmaxf(mx1, v.y); s1 += v.y;
    mx2 = fmaxf(mx2, v.z); s2 += v.z;
    mx3 = fmaxf(mx3, v.w); s3 += v.w;
    ushort4 u;
    u.x = f2bf(v.x); u.y = f2bf(v.y); u.z = f2bf(v.z); u.w = f2bf(v.w);
    *(ushort4*)&qb[(size_t)c * NN + n0] = u;
  }
  size_t pidx = ((size_t)(b * 16 + cch)) * NN + n0;
  float4 m4; m4.x = mx0; m4.y = mx1; m4.z = mx2; m4.w = mx3;
  float4 s4; s4.x = s0;  s4.y = s1;  s4.z = s2;  s4.w = s3;
  *(float4*)&pmax[pidx] = m4;
  *(float4*)&psum[pidx] = s4;
}

// ---------------------------------------------------------------------------
// Kernel 1b: combine 16 channel-chunk partials -> x3 = max + mean
// grid: 72 blocks x 256 thr, 4 n per thread
// ---------------------------------------------------------------------------
__global__ __launch_bounds__(256) void k_prep2(const float* __restrict__ pmax,
                                               const float* __restrict__ psum,
                                               float* __restrict__ x3) {
  int bid = blockIdx.x;
  int b = bid / 9;
  int n0 = (bid % 9) * 1024 + threadIdx.x * 4;
  float4 mx = *(const float4*)&pmax[(size_t)(b * 16) * NN + n0];
  float4 sm = *(const float4*)&psum[(size_t)(b * 16) * NN + n0];
  for (int cch = 1; cch < 16; ++cch) {
    float4 m = *(const float4*)&pmax[(size_t)(b * 16 + cch) * NN + n0];
    float4 s = *(const float4*)&psum[(size_t)(b * 16 + cch) * NN + n0];
    mx.x = fmaxf(mx.x, m.x); mx.y = fmaxf(mx.y, m.y);
    mx.z = fmaxf(mx.z, m.z); mx.w = fmaxf(mx.w, m.w);
    sm.x += s.x; sm.y += s.y; sm.z += s.z; sm.w += s.w;
  }
  float4 o;
  o.x = mx.x + sm.x * (1.f / CC);
  o.y = mx.y + sm.y * (1.f / CC);
  o.z = mx.z + sm.z * (1.f / CC);
  o.w = mx.w + sm.w * (1.f / CC);
  *(float4*)&x3[(size_t)b * NN + n0] = o;
}

// ---------------------------------------------------------------------------
// Kernel 2: transpose qbf [b][c][n] -> qt [b][n][c]  (64x64 LDS tiles)
// grid: 8 * 8 * 144 = 9216 blocks x 256 thr
// ---------------------------------------------------------------------------
__global__ __launch_bounds__(256) void k_qt(const uint16_t* __restrict__ qbf,
                                            uint16_t* __restrict__ qt) {
  __shared__ uint16_t tile[64][68];  // pad to 68 to break bank conflicts
  int bid = blockIdx.x;
  int b = bid / 1152;
  int rem = bid % 1152;
  int d0 = (rem / 144) * 64;
  int n0 = (rem % 144) * 64;
  int t = threadIdx.x;
  int cg = (t & 15) * 4;  // 4-element column group
  int rr = t >> 4;        // 0..15
  const uint16_t* src = qbf + (size_t)b * CN + (size_t)d0 * NN + n0;
  for (int rb = 0; rb < 4; ++rb) {
    int d = rr + rb * 16;
    ushort4 v = *(const ushort4*)&src[(size_t)d * NN + cg];
    tile[d][cg + 0] = v.x; tile[d][cg + 1] = v.y;
    tile[d][cg + 2] = v.z; tile[d][cg + 3] = v.w;
  }
  __syncthreads();
  uint16_t* dst = qt + (size_t)b * CN + (size_t)n0 * CC + d0;
  for (int rb = 0; rb < 4; ++rb) {
    int n = rr + rb * 16;
    ushort4 v;
    v.x = tile[cg + 0][n]; v.y = tile[cg + 1][n];
    v.z = tile[cg + 2][n]; v.w = tile[cg + 3][n];
    *(ushort4*)&dst[(size_t)n * CC + cg] = v;
  }
}

// ---------------------------------------------------------------------------
// Kernel 3: GEMM1 split-K partials  epart[sk][b] = Q @ Q^T over K-chunk sk
// 128x128 tile, BK=32, 256 thr (4 waves 2x2, wave 64x64), XOR-swizzled LDS
// grid: 8 b * 16 tiles * 8 sk = 1024 blocks
// ---------------------------------------------------------------------------
__global__ __launch_bounds__(256) void k_gemm1(const uint16_t* __restrict__ q,
                                               float* __restrict__ epart) {
  __shared__ uint16_t As[128 * 32];
  __shared__ uint16_t Bs[128 * 32];
  int bid = blockIdx.x;
  int sk = bid & 7;
  int tile = (bid >> 3) & 15;
  int b = bid >> 7;
  int tmi = tile >> 2, tni = tile & 3;
  const uint16_t* Abase = q + (size_t)b * CN + (size_t)(tmi * 128) * NN;
  const uint16_t* Bbase = q + (size_t)b * CN + (size_t)(tni * 128) * NN;
  int tid = threadIdx.x, lane = tid & 63, wid = tid >> 6;
  int wm = (wid >> 1) * 64, wn = (wid & 1) * 64;
  int lr = lane & 15, lq = lane >> 4;
  // staging: thread's two 16B chunks of each 128x32 tile, XOR-swizzled src col
  int e0 = tid * 8;
  int r0 = e0 >> 5;
  int sl0 = ((e0 >> 3) & 3) ^ ((r0 >> 1) & 3);  // logical slot for phys slot
  int c0 = sl0 * 8;
  // second chunk: r1 = r0 + 64, (r1>>1)&3 == (r0>>1)&3 -> same swizzle
  int ldsb0 = tid * 8;          // == e0, linear LDS dest
  int ldsb1 = 2048 + ldsb0;
  // fragment read offsets (element index), physical slot = lq ^ ((row>>1)&3)
  int arow[4], brow[4];
  for (int i = 0; i < 4; ++i) { arow[i] = wm + i * 16 + lr; brow[i] = wn + i * 16 + lr; }
  f32x4 acc[4][4];
  for (int i = 0; i < 4; ++i)
    for (int j = 0; j < 4; ++j)
      for (int k = 0; k < 4; ++k) acc[i][j][k] = 0.f;

  int kbeg = sk * KCH;
  for (int k0 = kbeg; k0 < kbeg + KCH; k0 += 32) {
    GLDS16(Abase + (size_t)r0 * NN + k0 + c0, &As[ldsb0]);
    GLDS16(Abase + (size_t)(r0 + 64) * NN + k0 + c0, &As[ldsb1]);
    GLDS16(Bbase + (size_t)r0 * NN + k0 + c0, &Bs[ldsb0]);
    GLDS16(Bbase + (size_t)(r0 + 64) * NN + k0 + c0, &Bs[ldsb1]);
    __syncthreads();
    bf16x8 av[4], bv[4];
    for (int mr = 0; mr < 4; ++mr) {
      int r = arow[mr];
      av[mr] = *(const bf16x8*)&As[r * 32 + (lq ^ ((r >> 1) & 3)) * 8];
    }
    for (int nr = 0; nr < 4; ++nr) {
      int r = brow[nr];
      bv[nr] = *(const bf16x8*)&Bs[r * 32 + (lq ^ ((r >> 1) & 3)) * 8];
    }
    for (int mr = 0; mr < 4; ++mr)
      for (int nr = 0; nr < 4; ++nr)
        acc[mr][nr] = __builtin_amdgcn_mfma_f32_16x16x32_bf16(
            av[mr], bv[nr], acc[mr][nr], 0, 0, 0);
    __syncthreads();
  }
  float* ep = epart + ((size_t)(sk * BB + b)) * (CC * CC);
  for (int mr = 0; mr < 4; ++mr)
    for (int nr = 0; nr < 4; ++nr) {
      int col = tni * 128 + wn + nr * 16 + lr;
      for (int j = 0; j < 4; ++j) {
        int row = tmi * 128 + wm + mr * 16 + lq * 4 + j;
        ep[(size_t)row * CC + col] = acc[mr][nr][j];
      }
    }
}

// ---------------------------------------------------------------------------
// Kernel 4: sum SK partials + row softmax of exp(rowmin - e)/sum -> bf16 att
// 256 thr = 4 waves, one row per wave; grid: 8*512/4 = 1024 blocks
// ---------------------------------------------------------------------------
__global__ __launch_bounds__(256) void k_softmax(const float* __restrict__ epart,
                                                 uint16_t* __restrict__ att) {
  int wid = threadIdx.x >> 6;
  int lane = threadIdx.x & 63;
  int grow = blockIdx.x * 4 + wid;          // 0..4095
  int b = grow >> 9;
  int r = grow & 511;
  float4 v0 = {0.f, 0.f, 0.f, 0.f}, v1 = {0.f, 0.f, 0.f, 0.f};
  for (int sk = 0; sk < SK; ++sk) {
    const float* e = epart + ((size_t)(sk * BB + b)) * (CC * CC) + (size_t)r * CC;
    float4 a = *(const float4*)&e[lane * 8];
    float4 c = *(const float4*)&e[lane * 8 + 4];
    v0.x += a.x; v0.y += a.y; v0.z += a.z; v0.w += a.w;
    v1.x += c.x; v1.y += c.y; v1.z += c.z; v1.w += c.w;
  }
  float mn = fminf(fminf(fminf(v0.x, v0.y), fminf(v0.z, v0.w)),
                   fminf(fminf(v1.x, v1.y), fminf(v1.z, v1.w)));
  for (int off = 32; off; off >>= 1) mn = fminf(mn, __shfl_xor(mn, off));
  float p0 = __expf(mn - v0.x), p1 = __expf(mn - v0.y);
  float p2 = __expf(mn - v0.z), p3 = __expf(mn - v0.w);
  float p4 = __expf(mn - v1.x), p5 = __expf(mn - v1.y);
  float p6 = __expf(mn - v1.z), p7 = __expf(mn - v1.w);
  float s = ((p0 + p1) + (p2 + p3)) + ((p4 + p5) + (p6 + p7));
  for (int off = 32; off; off >>= 1) s += __shfl_xor(s, off);
  float inv = 1.f / s;
  ushort4 u0, u1;
  u0.x = f2bf(p0 * inv); u0.y = f2bf(p1 * inv);
  u0.z = f2bf(p2 * inv); u0.w = f2bf(p3 * inv);
  u1.x = f2bf(p4 * inv); u1.y = f2bf(p5 * inv);
  u1.z = f2bf(p6 * inv); u1.w = f2bf(p7 * inv);
  uint16_t* a = att + (size_t)grow * CC + lane * 8;
  *(ushort4*)&a[0] = u0;
  *(ushort4*)&a[4] = u1;
}

// ---------------------------------------------------------------------------
// Kernel 5: GEMM2  out = gamma * (x3[n] * (att @ q)[c,n]) + x
// A = att [512,512], B^T = qt [9216,512] (NT), K=512; XOR-swizzled LDS
// 128x128 tile, BK=32; grid: 8 * 4 * 72 = 2304 blocks
// ---------------------------------------------------------------------------
__global__ __launch_bounds__(256) void k_gemm2(const uint16_t* __restrict__ att,
                                               const uint16_t* __restrict__ qt,
                                               const float* __restrict__ x3,
                                               const float* __restrict__ x,
                                               const float* __restrict__ gamma,
                                               float* __restrict__ out) {
  __shared__ uint16_t As[128 * 32];
  __shared__ uint16_t Bs[128 * 32];
  int bid = blockIdx.x;
  int b = bid / 288;
  int rem = bid % 288;
  int tmi = rem / 72;   // c tile (0..3)
  int tni = rem % 72;   // n tile (0..71)
  const uint16_t* Abase = att + (size_t)b * CC * CC + (size_t)(tmi * 128) * CC;
  const uint16_t* Bbase = qt + (size_t)b * CN + (size_t)(tni * 128) * CC;
  int tid = threadIdx.x, lane = tid & 63, wid = tid >> 6;
  int wm = (wid >> 1) * 64, wn = (wid & 1) * 64;
  int lr = lane & 15, lq = lane >> 4;
  int e0 = tid * 8;
  int r0 = e0 >> 5;
  int sl0 = ((e0 >> 3) & 3) ^ ((r0 >> 1) & 3);
  int c0 = sl0 * 8;
  int ldsb0 = tid * 8;
  int ldsb1 = 2048 + ldsb0;
  int arow[4], brow[4];
  for (int i = 0; i < 4; ++i) { arow[i] = wm + i * 16 + lr; brow[i] = wn + i * 16 + lr; }
  f32x4 acc[4][4];
  for (int i = 0; i < 4; ++i)
    for (int j = 0; j < 4; ++j)
      for (int k = 0; k < 4; ++k) acc[i][j][k] = 0.f;

  for (int k0 = 0; k0 < CC; k0 += 32) {
    GLDS16(Abase + (size_t)r0 * CC + k0 + c0, &As[ldsb0]);
    GLDS16(Abase + (size_t)(r0 + 64) * CC + k0 + c0, &As[ldsb1]);
    GLDS16(Bbase + (size_t)r0 * CC + k0 + c0, &Bs[ldsb0]);
    GLDS16(Bbase + (size_t)(r0 + 64) * CC + k0 + c0, &Bs[ldsb1]);
    __syncthreads();
    bf16x8 av[4], bv[4];
    for (int mr = 0; mr < 4; ++mr) {
      int r = arow[mr];
      av[mr] = *(const bf16x8*)&As[r * 32 + (lq ^ ((r >> 1) & 3)) * 8];
    }
    for (int nr = 0; nr < 4; ++nr) {
      int r = brow[nr];
      bv[nr] = *(const bf16x8*)&Bs[r * 32 + (lq ^ ((r >> 1) & 3)) * 8];
    }
    for (int mr = 0; mr < 4; ++mr)
      for (int nr = 0; nr < 4; ++nr)
        acc[mr][nr] = __builtin_amdgcn_mfma_f32_16x16x32_bf16(
            av[mr], bv[nr], acc[mr][nr], 0, 0, 0);
    __syncthreads();
  }
  float g = gamma[0];
  const float* xb = x + (size_t)b * CN;
  const float* x3b = x3 + (size_t)b * NN;
  float* ob = out + (size_t)b * CN;
  for (int mr = 0; mr < 4; ++mr)
    for (int nr = 0; nr < 4; ++nr) {
      int n = tni * 128 + wn + nr * 16 + lr;
      float s = x3b[n];
      for (int j = 0; j < 4; ++j) {
        int c = tmi * 128 + wm + mr * 16 + lq * 4 + j;
        size_t idx = (size_t)c * NN + n;
        ob[idx] = g * (s * acc[mr][nr][j]) + xb[idx];
      }
    }
}

// ---------------------------------------------------------------------------
extern "C" void kernel_launch(void* const* d_in, const int* in_sizes, int n_in,
                              void* d_out, int out_size, void* d_ws, size_t ws_size,
                              hipStream_t stream) {
  const float* x = (const float*)d_in[0];
  const float* gamma = (const float*)d_in[1];
  float* out = (float*)d_out;
  char* ws = (char*)d_ws;
  // workspace layout (160,727,040 B used; stays within proven 163.87 MB):
  //   qbf  @0          75,497,472   bf16 [b][c][n], dead after gemm1
  //   qt   @75497472   75,497,472   bf16 [b][n][c], read by gemm2
  //   pmax @150994944   4,718,592   f32 [b][16][n], dead after prep2
  //   psum @155713536   4,718,592   f32 [b][16][n], dead after prep2
  //   att  @150994944   4,194,304   bf16 [b][c][c] (aliases pmax; written
  //                                 by softmax after pmax is dead)
  //   x3   @160432128     294,912   f32 [b][n]
  // GEMM1 split-K partials (8 x 8.4 MB = 67 MB, f32) live in d_out, which is
  // dead scratch until gemm2's epilogue overwrites it completely.
  uint16_t* qbf  = (uint16_t*)(ws);
  uint16_t* qt   = (uint16_t*)(ws + 75497472);
  float*    pmax = (float*)(ws + 150994944);
  float*    psum = (float*)(ws + 155713536);
  uint16_t* att  = (uint16_t*)(ws + 150994944);
  float*    x3   = (float*)(ws + 160432128);
  float*    epart = (float*)d_out;

  k_prep1<<<1152, 256, 0, stream>>>(x, qbf, pmax, psum);
  k_prep2<<<72, 256, 0, stream>>>(pmax, psum, x3);
  k_qt<<<9216, 256, 0, stream>>>(qbf, qt);
  k_gemm1<<<1024, 256, 0, stream>>>(qbf, epart);
  k_softmax<<<1024, 256, 0, stream>>>(epart, att);
  k_gemm2<<<2304, 256, 0, stream>>>(att, qt, x3, x, gamma, out);
}